// Round 12
// baseline (74.307 us; speedup 1.0000x reference)
//
#include <hip/hip_runtime.h>

typedef unsigned int uint;

#define HW (512 * 512)
#define NIMG 64
#define NUQ 6
#define RSTRIDE 528               // ring row: 512 px + 16 sentinel bytes
#define RINGB 32768               // ring base; 32 rows x 528 = 16896 B
#define SMEMB (32768 + 32 * RSTRIDE)   // 49664

// 8 reference offsets -> 6 unique, weighted; (1,-1) stored as (-1,1)
// (transpose-equivalent under final P+P^T symmetrization).
// tag0: u0 (0,1) lo, u3 (-1,1) hi | tag1: u1 (1,1) lo, u4 (0,2) hi
// tag2: u2 (1,0) lo, u5 (2,0) hi
__device__ __constant__ float UOFF_W[NUQ] = {1.f, 2.f, 1.f, 2.f, 1.f, 1.f};
__device__ __constant__ float NPAIRS[NUQ] = {
    512.f * 511.f, 511.f * 511.f, 511.f * 512.f,
    511.f * 511.f, 512.f * 510.f, 510.f * 512.f};

__device__ __forceinline__ uint q1f(float a, float b, float c) {
    float t = fmaf(a + b + c, 5.1666665f, 15.5f);   // ((a+b+c)/3+1)*0.5*31
    t = fminf(fmaxf(t, 0.0f), 31.0f);
    return (uint)t;                                  // trunc = astype(int32)
}

// ---- fused: 512-thread blocks, 64-row strips; R4 skeleton, perm hist ----
__global__ __launch_bounds__(512, 4) void glcm_fused(
    const float* __restrict__ in, uint* __restrict__ wire) {
    __shared__ __align__(16) unsigned char smem[SMEMB];
    const int tid = threadIdx.x;
    const int b = blockIdx.x >> 3;
    const int sp = blockIdx.x & 7;
    const int rs = sp * 64;               // 64 anchor rows per block
    const float* ib = in + (size_t)b * (3 * HW);
    const int lrow = tid >> 6;            // 0..7: row within 8-row chunk
    const int lcol = (tid & 63) << 3;     // 8 px per thread

    {   // zero 32 KB hist (junk half included)
        uint4 z = make_uint4(0, 0, 0, 0);
        #pragma unroll
        for (int q = 0; q < 4; ++q)
            *(uint4*)(smem + tid * 16 + q * 8192) = z;
    }
    __syncthreads();

    float4 A0, B0, A1, B1, A2, B2;

    // issue 6 float4 loads for chunk c (rows rs-2+8c .. +7); use deferred
    auto issueL = [&](int c) {
        int R = rs - 2 + 8 * c + lrow;
        int Rc = min(max(R, 0), 511);     // clamped rows loaded, never written
        const float* p = ib + ((size_t)Rc << 9) + lcol;
        A0 = *(const float4*)(p);
        B0 = *(const float4*)(p + 4);
        A1 = *(const float4*)(p + HW);
        B1 = *(const float4*)(p + HW + 4);
        A2 = *(const float4*)(p + 2 * HW);
        B2 = *(const float4*)(p + 2 * HW + 4);
    };

    // quantize chunk c into ring (bytes pre-shifted <<2) + sentinel pads
    auto quantW = [&](int c) {
        int R = rs - 2 + 8 * c + lrow;
        if (R >= 0 && R <= 511 && R <= rs + 65) {
            uint q0 = (q1f(A0.x, A1.x, A2.x) << 2)
                    | (q1f(A0.y, A1.y, A2.y) << 10)
                    | (q1f(A0.z, A1.z, A2.z) << 18)
                    | (q1f(A0.w, A1.w, A2.w) << 26);
            uint q1_ = (q1f(B0.x, B1.x, B2.x) << 2)
                     | (q1f(B0.y, B1.y, B2.y) << 10)
                     | (q1f(B0.z, B1.z, B2.z) << 18)
                     | (q1f(B0.w, B1.w, B2.w) << 26);
            unsigned char* rw = smem + RINGB + ((R - rs + 2) & 31) * RSTRIDE;
            *(uint2*)(rw + lcol) = make_uint2(q0, q1_);
            if ((tid & 63) == 63)         // sentinel cols 512..527
                *(uint4*)(rw + 512) = make_uint4(0x80808080u, 0x80808080u,
                                                 0x80808080u, 0x80808080u);
        }
    };

    // histogram chunk h: anchors rs+8h .. +7; 2 rounds x (4 rows x 128 dwords)
    auto histC = [&](int h) {
        #pragma unroll
        for (int rr = 0; rr < 2; ++rr) {
            const int task = tid + (rr << 9);
            const int R = rs + 8 * h + (task >> 7);           // wave-uniform
            const int v = (R - rs + 2) & 31;
            const int dq = task & 127;
            const unsigned char* ring = smem + RINGB;
            const uint* rowL   = (const uint*)(ring + v * RSTRIDE);
            const uint* rowLm  = (const uint*)(ring + ((v - 1) & 31) * RSTRIDE);
            const uint* rowLp  = (const uint*)(ring + ((v + 1) & 31) * RSTRIDE);
            const uint* rowLpp = (const uint*)(ring + ((v + 2) & 31) * RSTRIDE);
            uint A  = rowL[dq],  A1 = rowL[dq + 1];   // dq=127 -> [128] = pad
            uint Bm = rowLp[dq], B1 = rowLp[dq + 1];
            uint Cm = rowLm[dq], C1 = rowLm[dq + 1];
            uint D  = rowLpp[dq];

            // stored j-field = (j + 3i) & 31 (bank mix, bijective per i);
            // perm {i<<2, j'<<2|sent} -> addr = i<<10 | sent<<7 | j'<<2;
            // sentinel bit7 -> junk half of the 256B (i,tag) block.
            auto pp4 = [&](uint IW, uint JW, int tagoff, uint inc) {
                uint jm = (JW >> 2) & 0x1F1F1F1Fu;
                uint im = (IW >> 2) & 0x1F1F1F1Fu;
                uint s  = (jm + im + (im << 1)) & 0x1F1F1F1Fu;  // j+3i, no carry
                uint J2 = (s << 2) | (JW & 0x80808080u);
                uint a0 = __builtin_amdgcn_perm(IW, J2, 0x0C0C0400u);
                uint a1 = __builtin_amdgcn_perm(IW, J2, 0x0C0C0501u);
                uint a2 = __builtin_amdgcn_perm(IW, J2, 0x0C0C0602u);
                uint a3 = __builtin_amdgcn_perm(IW, J2, 0x0C0C0703u);
                atomicAdd((uint*)(smem + tagoff + a0), inc);
                atomicAdd((uint*)(smem + tagoff + a1), inc);
                atomicAdd((uint*)(smem + tagoff + a2), inc);
                atomicAdd((uint*)(smem + tagoff + a3), inc);
            };
            pp4(A, __builtin_amdgcn_alignbyte(A1, A, 1), 0, 1u);             // u0 (0,1)
            if (R < 511) {
                pp4(A, __builtin_amdgcn_alignbyte(B1, Bm, 1), 256, 1u);      // u1 (1,1)
                pp4(A, Bm, 512, 1u);                                         // u2 (1,0)
            }
            if (R >= 1)
                pp4(A, __builtin_amdgcn_alignbyte(C1, Cm, 1), 0, 65536u);    // u3 (-1,1)
            pp4(A, __builtin_amdgcn_alignbyte(A1, A, 2), 256, 65536u);       // u4 (0,2)
            if (R < 510) pp4(A, D, 512, 65536u);                             // u5 (2,0)
        }
    };

    // chunks c=0..8 load rows rs-2 .. rs+65 (clamped); hist h=0..7
    for (int c = 0; c <= 9; ++c) {
        if (c <= 8) issueL(c);            // loads issue; vmcnt waited in quantW
        if (c >= 2) histC(c - 2);         // DS+VALU work hides load latency
        if (c <= 8) quantW(c);
        __syncthreads();
    }

    // flush valid bins -> 3072-dword wire, un-mixing the stored j-field
    uint* hw = wire + (size_t)blockIdx.x * 3072;
    const uint* hist = (const uint*)smem;
    #pragma unroll
    for (int qq = 0; qq < 6; ++qq) {
        int o = tid + qq * 512;           // o = tag*1024 + i*32 + j
        int tg = o >> 10, ij = o & 1023;
        int i2 = ij >> 5, j = ij & 31;
        hw[o] = hist[(i2 << 8) | (tg << 6) | ((j + 3 * i2) & 31)];
    }
}

// ---- features + weighted offset average, one block per image ----
__global__ __launch_bounds__(256) void feature_out_kernel(
    const uint* __restrict__ wire, float* __restrict__ out) {
    const int b = blockIdx.x;
    __shared__ uint cnt[NUQ][1024];       // 24 KB
    __shared__ float fred[NUQ][4];
    const int tid = threadIdx.x, wid = tid >> 6, lane = tid & 63;

    for (int u = wid; u < NUQ; u += 4) {
        const int tg = (u < 3) ? u : u - 3;
        const int sh = (u < 3) ? 0 : 16;
        const uint* p = wire + (size_t)b * (8 * 3072) + tg * 1024;
        for (int ij = lane; ij < 1024; ij += 64) {
            uint acc = 0;
            #pragma unroll
            for (int st = 0; st < 8; ++st)
                acc += (p[(size_t)st * 3072 + ij] >> sh) & 0xFFFFu;
            cnt[u][ij] = acc;
        }
    }
    __syncthreads();

    for (int u = wid; u < NUQ; u += 4) {
        const float inv_total = 1.0f / (2.0f * NPAIRS[u]);
        float c_sum = 0, h_sum = 0, e_sum = 0, m1 = 0, m2 = 0, m12 = 0;
        for (int k = lane; k < 1024; k += 64) {
            int i = k >> 5, j = k & 31;
            float sym = (float)(cnt[u][k] + cnt[u][(j << 5) | i]);
            float P = sym * inv_total;
            float d = (float)(i - j);
            float d2 = d * d;
            float fi = (float)i, fj = (float)j;
            c_sum += P * d2;
            h_sum += P / (1.0f + d2);
            e_sum += P * P;
            m1 += P * fi; m2 += P * fi * fi; m12 += P * fi * fj;
        }
        #pragma unroll
        for (int sft = 32; sft > 0; sft >>= 1) {
            c_sum += __shfl_down(c_sum, sft);
            h_sum += __shfl_down(h_sum, sft);
            e_sum += __shfl_down(e_sum, sft);
            m1 += __shfl_down(m1, sft);
            m2 += __shfl_down(m2, sft);
            m12 += __shfl_down(m12, sft);
        }
        if (lane == 0) {
            float mu = m1, var = m2 - mu * mu, cov = m12 - mu * mu;
            float corr = (var > 1e-15f) ? cov / var : 1.0f;  // std_i*std_j = var
            fred[u][0] = c_sum; fred[u][1] = h_sum;
            fred[u][2] = sqrtf(e_sum); fred[u][3] = corr;
        }
    }
    __syncthreads();
    if (tid < 4) {
        float acc = 0.f;
        #pragma unroll
        for (int u = 0; u < NUQ; ++u) acc += UOFF_W[u] * fred[u][tid];
        out[tid * NIMG + b] = acc * 0.125f;
    }
}

extern "C" void kernel_launch(void* const* d_in, const int* in_sizes, int n_in,
                              void* d_out, int out_size, void* d_ws, size_t ws_size,
                              hipStream_t stream) {
    const float* images = (const float*)d_in[0];
    float* out = (float*)d_out;
    uint* wire = (uint*)d_ws;             // 512 blocks x 3072 u32 = 6.3 MB

    glcm_fused<<<NIMG * 8, 512, 0, stream>>>(images, wire);
    feature_out_kernel<<<NIMG, 256, 0, stream>>>(wire, out);
}